// Round 7
// baseline (39.999 us; speedup 1.0000x reference)
//
#include <hip/hip_runtime.h>
#include <hip/hip_bf16.h>
#include <stdint.h>

#define NN 1024
#define EMBED 256
#define NHEAD 8
#define NHID 32
#define SLOPE 0.2f

// ---------------------------------------------------------------------------
// Kernel 1, grid 544:
//   blocks [0,512)  : GEMM 32x32 tile, BK=32, 2x2 micro-tile, reg-prefetch.
//                     2 blocks/CU -> 2 waves/SIMD (TLP to hide LDS/L2 latency)
//   blocks [512,544): adjacency bitmask, 32 rows/block via LDS accumulation
// ---------------------------------------------------------------------------
__global__ __launch_bounds__(256) void k_prep(const float* __restrict__ h,
                                              const float* __restrict__ Wl,
                                              const float* __restrict__ Wr,
                                              const int* __restrict__ ei, int E,
                                              float* __restrict__ gl,
                                              float* __restrict__ gr,
                                              unsigned int* __restrict__ adj) {
    const int blk = blockIdx.x;
    const int t = threadIdx.x;

    if (blk < 512) {
        const int z  = blk >> 8;              // 0: W_l -> gl, 1: W_r -> gr
        const int rem = blk & 255;
        const int bm = (rem >> 3) * 32;       // 32 row-tiles
        const int bn = (rem & 7) * 32;        // 8 col-tiles
        const float* W = z ? Wr : Wl;
        float* outg = z ? gr : gl;

        __shared__ float As[32][33];          // [k][m]
        __shared__ float Bs[32][33];          // [k][n]

        const int lr = t >> 3;                // loader row 0..31
        const int lc = (t & 7) << 2;          // loader col {0,4,...,28}
        const float* Ap = &h[(bm + lr) * EMBED + lc];
        const float* Bp = &W[lr * EMBED + bn + lc];

        const int ty = t >> 4;                // 0..15 -> rows ty*2, ty*2+1
        const int tx = t & 15;                // 0..15 -> cols tx*2, tx*2+1

        float acc00 = 0.f, acc01 = 0.f, acc10 = 0.f, acc11 = 0.f;

        float4 a_reg = *reinterpret_cast<const float4*>(Ap);
        float4 b_reg = *reinterpret_cast<const float4*>(Bp);

        for (int k0 = 0; k0 < EMBED; k0 += 32) {
            As[lc + 0][lr] = a_reg.x; As[lc + 1][lr] = a_reg.y;
            As[lc + 2][lr] = a_reg.z; As[lc + 3][lr] = a_reg.w;
            Bs[lr][lc + 0] = b_reg.x; Bs[lr][lc + 1] = b_reg.y;
            Bs[lr][lc + 2] = b_reg.z; Bs[lr][lc + 3] = b_reg.w;
            __syncthreads();
            if (k0 + 32 < EMBED) {            // register-prefetch next K tile
                a_reg = *reinterpret_cast<const float4*>(Ap + k0 + 32);
                b_reg = *reinterpret_cast<const float4*>(Bp + (size_t)(k0 + 32) * EMBED);
            }
#pragma unroll
            for (int kk = 0; kk < 32; ++kk) {
                float a0 = As[kk][ty * 2 + 0];
                float a1 = As[kk][ty * 2 + 1];
                float b0 = Bs[kk][tx * 2 + 0];
                float b1 = Bs[kk][tx * 2 + 1];
                acc00 += a0 * b0; acc01 += a0 * b1;
                acc10 += a1 * b0; acc11 += a1 * b1;
            }
            __syncthreads();
        }
        *reinterpret_cast<float2*>(&outg[(bm + ty * 2 + 0) * EMBED + bn + tx * 2]) =
            make_float2(acc00, acc01);
        *reinterpret_cast<float2*>(&outg[(bm + ty * 2 + 1) * EMBED + bn + tx * 2]) =
            make_float2(acc10, acc11);
    } else {
        // adjacency build: rows [lo, lo+32), 1024 uint words in LDS
        const int lo = (blk - 512) * 32;
        __shared__ unsigned int lads[1024];
#pragma unroll
        for (int u = 0; u < 4; ++u) lads[t + u * 256] = 0u;
        __syncthreads();

        const int4* ei4 = reinterpret_cast<const int4*>(ei);  // 2 edges / int4
        const int nvec = E >> 1;                              // 16384
        for (int base = 0; base < nvec; base += 2048) {
#pragma unroll 8
            for (int u = 0; u < 8; ++u) {
                int4 v = ei4[base + u * 256 + t];
                int r0 = v.x - lo;
                if ((unsigned)r0 < 32u)
                    atomicOr(&lads[r0 * 32 + ((unsigned)v.y >> 5)], 1u << (v.y & 31));
                int r1 = v.z - lo;
                if ((unsigned)r1 < 32u)
                    atomicOr(&lads[r1 * 32 + ((unsigned)v.w >> 5)], 1u << (v.w & 31));
            }
        }
        __syncthreads();
#pragma unroll
        for (int u = 0; u < 4; ++u)
            adj[lo * 32 + t + u * 256] = lads[t + u * 256];
    }
}

// ---------------------------------------------------------------------------
// Kernel 2: per-destination-row sparse softmax + aggregate (1 row / block).
// Thread t owns feature f=t (head t/32, dim t%32). Wave 0 compacts the set
// bits into an LDS neighbor list, then unroll-4 online softmax with
// one-group-ahead prefetch. 1024 blocks = 4 waves/SIMD.
// ---------------------------------------------------------------------------
__global__ __launch_bounds__(256) void k_attn(const float* __restrict__ gl,
                                              const float* __restrict__ gr,
                                              const unsigned int* __restrict__ adj,
                                              const float* __restrict__ attn_w,
                                              float* __restrict__ out) {
    const int i = blockIdx.x;
    const int t = threadIdx.x;

    __shared__ int nbr[NN];
    __shared__ int cnt_s;

    if (t < 64) {
        unsigned int w = (t < 32) ? adj[i * 32 + t] : 0u;
        int c = __popc(w);
        int pre = c;
#pragma unroll
        for (int d = 1; d < 64; d <<= 1) {
            int v = __shfl_up(pre, d);
            if (t >= d) pre += v;
        }
        int off = pre - c;          // exclusive prefix
        if (t == 63) cnt_s = pre;   // total count
        while (w) {
            int b = __builtin_ctz(w);
            w &= w - 1;
            nbr[off++] = t * 32 + b;
        }
    }
    __syncthreads();

    const int cnt = cnt_s;
    const float grv = gr[i * EMBED + t];
    const float aw = attn_w[t & 31];

    float m = -3e38f;
    float s = 0.f;
    float acc = 0.f;

    // prefetch group 0
    float g[4];
#pragma unroll
    for (int u = 0; u < 4; ++u) {
        int e = u < cnt ? u : 0;
        g[u] = gl[nbr[e] * EMBED + t];
    }

    for (int e0 = 0; e0 < cnt; e0 += 4) {
        float cg[4];
#pragma unroll
        for (int u = 0; u < 4; ++u) cg[u] = g[u];
        // prefetch next group (independent of the update chain below)
#pragma unroll
        for (int u = 0; u < 4; ++u) {
            int e = e0 + 4 + u;
            e = e < cnt ? e : 0;
            g[u] = gl[nbr[e] * EMBED + t];
        }
        // scores: 4 independent shuffle-reduce chains
        float p[4];
#pragma unroll
        for (int u = 0; u < 4; ++u) {
            float x = cg[u] + grv;
            float pv = (x > 0.f ? x : SLOPE * x) * aw;
            pv += __shfl_xor(pv, 1);
            pv += __shfl_xor(pv, 2);
            pv += __shfl_xor(pv, 4);
            pv += __shfl_xor(pv, 8);
            pv += __shfl_xor(pv, 16);
            p[u] = pv;
        }
        // online softmax update (wave-uniform bounds check)
#pragma unroll
        for (int u = 0; u < 4; ++u) {
            if (e0 + u < cnt) {
                float mn = fmaxf(m, p[u]);
                float sc = __expf(m - mn);
                float ev = __expf(p[u] - mn);
                s = s * sc + ev;
                acc = acc * sc + ev * cg[u];
                m = mn;
            }
        }
    }
    out[i * EMBED + t] = acc / s;
}

extern "C" void kernel_launch(void* const* d_in, const int* in_sizes, int n_in,
                              void* d_out, int out_size, void* d_ws, size_t ws_size,
                              hipStream_t stream) {
    const float* h  = (const float*)d_in[0];
    const int*   ei = (const int*)d_in[1];
    const float* Wl = (const float*)d_in[2];
    const float* Wr = (const float*)d_in[3];
    const float* aw = (const float*)d_in[4];
    float* out = (float*)d_out;
    const int E = in_sizes[1] / 2;

    unsigned int* adj = (unsigned int*)d_ws;                 // 128 KB
    float* gl = (float*)((char*)d_ws + 131072);              // 1 MB
    float* gr = gl + NN * EMBED;                             // 1 MB

    k_prep<<<544, 256, 0, stream>>>(h, Wl, Wr, ei, E, gl, gr, adj);
    k_attn<<<NN, 256, 0, stream>>>(gl, gr, adj, aw, out);
}

// Round 8
// 36.935 us; speedup vs baseline: 1.0830x; 1.0830x over previous
//
#include <hip/hip_runtime.h>
#include <hip/hip_bf16.h>
#include <stdint.h>

#define NN 1024
#define EMBED 256
#define NHEAD 8
#define NHID 32
#define SLOPE 0.2f
#define DEGMAX 64

// DPP-based lane permute (VALU pipe, not LDS). CTRL: 0xB1=xor1, 0x4E=xor2,
// 0x141=row_half_mirror (pairs 8-groups), 0x140=row_mirror (pairs 16-groups).
template <int CTRL>
__device__ __forceinline__ float dpp_mov(float x) {
    int r = __builtin_amdgcn_update_dpp(0, __float_as_int(x), CTRL, 0xF, 0xF, true);
    return __int_as_float(r);
}
// all-reduce sum over each aligned 32-lane group
__device__ __forceinline__ float group32_sum(float v) {
    v += dpp_mov<0xB1>(v);    // + lane^1   (quad_perm 1,0,3,2)
    v += dpp_mov<0x4E>(v);    // + lane^2   (quad_perm 2,3,0,1)
    v += dpp_mov<0x141>(v);   // + mirror within 8  -> sum over 8
    v += dpp_mov<0x140>(v);   // + mirror within 16 -> sum over 16
    v += __shfl_xor(v, 16);   // pair 16-groups     -> sum over 32
    return v;
}

// ---------------------------------------------------------------------------
// Kernel 1, grid 160:
//   blocks [0,128)  : GEMM 64x64 tile, BK=16, 4x4 micro-tile, reg-prefetch,
//                     b128-aligned LDS (stride 68)
//   blocks [128,160): adjacency bitmask (LDS) -> compacted CSR neighbor lists
// ---------------------------------------------------------------------------
__global__ __launch_bounds__(256) void k_prep(const float* __restrict__ h,
                                              const float* __restrict__ Wl,
                                              const float* __restrict__ Wr,
                                              const int* __restrict__ ei, int E,
                                              float* __restrict__ gl,
                                              float* __restrict__ gr,
                                              int* __restrict__ nbrg,
                                              int* __restrict__ cntg) {
    const int blk = blockIdx.x;
    const int t = threadIdx.x;

    if (blk < 128) {
        const int z  = blk & 1;
        const int bn = ((blk >> 1) & 3) * 64;
        const int bm = (blk >> 3) * 64;
        const float* W = z ? Wr : Wl;
        float* outg = z ? gr : gl;
        const int tx = t & 15;
        const int ty = t >> 4;

        __shared__ float As[16][68];   // [k][m], stride 68 -> 16B-aligned rows
        __shared__ float Bs[16][68];   // [k][n]

        float acc[4][4];
#pragma unroll
        for (int i = 0; i < 4; ++i)
#pragma unroll
            for (int j = 0; j < 4; ++j) acc[i][j] = 0.f;

        const int ar = t >> 2, ac = (t & 3) << 2;    // A: 64 rows x 16 k
        const int br = t >> 4, bc = (t & 15) << 2;   // B: 16 k x 64 cols
        const float* Ap = &h[(bm + ar) * EMBED + ac];
        const float* Bp = &W[br * EMBED + bn + bc];

        float4 a_reg = *reinterpret_cast<const float4*>(Ap);
        float4 b_reg = *reinterpret_cast<const float4*>(Bp);

        for (int k0 = 0; k0 < EMBED; k0 += 16) {
            As[ac + 0][ar] = a_reg.x; As[ac + 1][ar] = a_reg.y;
            As[ac + 2][ar] = a_reg.z; As[ac + 3][ar] = a_reg.w;
            Bs[br][bc + 0] = b_reg.x; Bs[br][bc + 1] = b_reg.y;
            Bs[br][bc + 2] = b_reg.z; Bs[br][bc + 3] = b_reg.w;
            __syncthreads();
            if (k0 + 16 < EMBED) {     // register-prefetch next K tile
                a_reg = *reinterpret_cast<const float4*>(Ap + k0 + 16);
                b_reg = *reinterpret_cast<const float4*>(Bp + (size_t)(k0 + 16) * EMBED);
            }
#pragma unroll
            for (int kk = 0; kk < 16; ++kk) {
                float4 av = *reinterpret_cast<const float4*>(&As[kk][ty * 4]);
                float4 bv = *reinterpret_cast<const float4*>(&Bs[kk][tx * 4]);
                float a[4] = {av.x, av.y, av.z, av.w};
                float b[4] = {bv.x, bv.y, bv.z, bv.w};
#pragma unroll
                for (int i = 0; i < 4; ++i)
#pragma unroll
                    for (int j = 0; j < 4; ++j) acc[i][j] += a[i] * b[j];
            }
            __syncthreads();
        }
#pragma unroll
        for (int i = 0; i < 4; ++i) {
            float4 v = make_float4(acc[i][0], acc[i][1], acc[i][2], acc[i][3]);
            *reinterpret_cast<float4*>(&outg[(bm + ty * 4 + i) * EMBED + bn + tx * 4]) = v;
        }
    } else {
        // ---- adjacency bitmask + CSR compaction for rows [lo, lo+32) -------
        const int lo = (blk - 128) * 32;
        __shared__ unsigned int lads[1024];
#pragma unroll
        for (int u = 0; u < 4; ++u) lads[t + u * 256] = 0u;
        __syncthreads();

        const int4* ei4 = reinterpret_cast<const int4*>(ei);  // 2 edges / int4
        const int nvec = E >> 1;
        int base = 0;
        for (; base + 2048 <= nvec; base += 2048) {
#pragma unroll 8
            for (int u = 0; u < 8; ++u) {
                int4 v = ei4[base + u * 256 + t];
                int r0 = v.x - lo;
                if ((unsigned)r0 < 32u)
                    atomicOr(&lads[r0 * 32 + ((unsigned)v.y >> 5)], 1u << (v.y & 31));
                int r1 = v.z - lo;
                if ((unsigned)r1 < 32u)
                    atomicOr(&lads[r1 * 32 + ((unsigned)v.w >> 5)], 1u << (v.w & 31));
            }
        }
        for (int idx = base + t; idx < nvec; idx += 256) {
            int4 v = ei4[idx];
            int r0 = v.x - lo;
            if ((unsigned)r0 < 32u)
                atomicOr(&lads[r0 * 32 + ((unsigned)v.y >> 5)], 1u << (v.y & 31));
            int r1 = v.z - lo;
            if ((unsigned)r1 < 32u)
                atomicOr(&lads[r1 * 32 + ((unsigned)v.w >> 5)], 1u << (v.w & 31));
        }
        __syncthreads();

        // compact: wave wv handles rows wv*8 .. wv*8+7
        const int wv = t >> 6, ln = t & 63;
        for (int rl = wv * 8; rl < wv * 8 + 8; ++rl) {
            unsigned int w = (ln < 32) ? lads[rl * 32 + ln] : 0u;
            int c = __popc(w);
            int pre = c;
#pragma unroll
            for (int d = 1; d < 32; d <<= 1) {
                int v = __shfl_up(pre, d);
                if (ln >= d) pre += v;
            }
            int tot = __shfl(pre, 31);          // total over lanes 0..31
            int off = pre - c;                  // exclusive prefix
            if (ln == 0) cntg[lo + rl] = tot;
            while (w) {
                int b = __builtin_ctz(w);
                w &= w - 1;
                if (off < DEGMAX) nbrg[(lo + rl) * DEGMAX + off] = ln * 32 + b;
                ++off;
            }
        }
    }
}

// ---------------------------------------------------------------------------
// Kernel 2: per-destination-row softmax + aggregate, CSR-direct.
// 1024 blocks; thread t owns feature t (head t/32, dim t%32). Unroll-4 with
// one-group-ahead prefetch; DPP group-sum; batched online-softmax update
// (1 rescale + 4 independent exps per 4 edges).
// ---------------------------------------------------------------------------
__global__ __launch_bounds__(256) void k_attn(const float* __restrict__ gl,
                                              const float* __restrict__ gr,
                                              const int* __restrict__ nbrg,
                                              const int* __restrict__ cntg,
                                              const float* __restrict__ attn_w,
                                              float* __restrict__ out) {
    const int i = blockIdx.x;
    const int t = threadIdx.x;

    __shared__ int nbr_s[DEGMAX];
    __shared__ int cnt_sh;

    if (t == 0) cnt_sh = cntg[i];
    if (t < DEGMAX) nbr_s[t] = nbrg[i * DEGMAX + t];
    __syncthreads();

    const int cnt = cnt_sh;                 // >= 1 (self-loop)
    const float grv = gr[i * EMBED + t];
    const float aw = attn_w[t & 31];

    float m = -3e38f, s = 0.f, acc = 0.f;

    float g[4];
#pragma unroll
    for (int u = 0; u < 4; ++u) {
        int e = (u < cnt) ? u : cnt - 1;
        g[u] = gl[nbr_s[e] * EMBED + t];
    }

    for (int e0 = 0; e0 < cnt; e0 += 4) {
        float cg[4];
#pragma unroll
        for (int u = 0; u < 4; ++u) cg[u] = g[u];
        // prefetch next group (independent of everything below)
#pragma unroll
        for (int u = 0; u < 4; ++u) {
            int e = e0 + 4 + u;
            e = (e < cnt) ? e : cnt - 1;
            g[u] = gl[nbr_s[e] * EMBED + t];
        }
        // scores: 4 independent DPP-reduce chains (VALU pipe)
        float p[4];
#pragma unroll
        for (int u = 0; u < 4; ++u) {
            float x = cg[u] + grv;
            p[u] = group32_sum((x > 0.f ? x : SLOPE * x) * aw);
        }
        // batched online-softmax: one rescale per 4 edges
        float pm = p[0];
#pragma unroll
        for (int u = 1; u < 4; ++u)
            if (e0 + u < cnt) pm = fmaxf(pm, p[u]);
        float mn = fmaxf(m, pm);
        float sc = __expf(m - mn);
        float ev[4];
#pragma unroll
        for (int u = 0; u < 4; ++u)
            ev[u] = (e0 + u < cnt) ? __expf(p[u] - mn) : 0.f;
        s = s * sc + ((ev[0] + ev[1]) + (ev[2] + ev[3]));
        acc = acc * sc + ((ev[0] * cg[0] + ev[1] * cg[1]) + (ev[2] * cg[2] + ev[3] * cg[3]));
        m = mn;
    }
    out[i * EMBED + t] = acc / s;
}

extern "C" void kernel_launch(void* const* d_in, const int* in_sizes, int n_in,
                              void* d_out, int out_size, void* d_ws, size_t ws_size,
                              hipStream_t stream) {
    const float* h  = (const float*)d_in[0];
    const int*   ei = (const int*)d_in[1];
    const float* Wl = (const float*)d_in[2];
    const float* Wr = (const float*)d_in[3];
    const float* aw = (const float*)d_in[4];
    float* out = (float*)d_out;
    const int E = in_sizes[1] / 2;

    int* nbrg = (int*)d_ws;                                    // 256 KB
    int* cntg = (int*)((char*)d_ws + NN * DEGMAX * 4);         // 4 KB
    float* gl = (float*)((char*)d_ws + NN * DEGMAX * 4 + 4096);  // 1 MB
    float* gr = gl + NN * EMBED;                               // 1 MB

    k_prep<<<160, 256, 0, stream>>>(h, Wl, Wr, ei, E, gl, gr, nbrg, cntg);
    k_attn<<<NN, 256, 0, stream>>>(gl, gr, nbrg, cntg, aw, out);
}

// Round 9
// 36.845 us; speedup vs baseline: 1.0856x; 1.0024x over previous
//
#include <hip/hip_runtime.h>
#include <hip/hip_bf16.h>
#include <stdint.h>

#define NN 1024
#define EMBED 256
#define NHEAD 8
#define NHID 32
#define SLOPE 0.2f
#define DEGMAX 64

typedef __attribute__((ext_vector_type(8))) short short8;
typedef __attribute__((ext_vector_type(4))) float f32x4;

__device__ __forceinline__ unsigned short f32_to_bf16(float f) {
    unsigned int u = __float_as_uint(f);
    unsigned int r = (u + 0x7FFFu + ((u >> 16) & 1u)) >> 16;
    return (unsigned short)r;
}
__device__ __forceinline__ float bf16_to_f32(unsigned short h) {
    return __uint_as_float(((unsigned int)h) << 16);
}

// DPP lane permutes for the 32-lane group reduce in k_attn
template <int CTRL>
__device__ __forceinline__ float dpp_mov(float x) {
    int r = __builtin_amdgcn_update_dpp(0, __float_as_int(x), CTRL, 0xF, 0xF, true);
    return __int_as_float(r);
}
__device__ __forceinline__ float group32_sum(float v) {
    v += dpp_mov<0xB1>(v);
    v += dpp_mov<0x4E>(v);
    v += dpp_mov<0x141>(v);
    v += dpp_mov<0x140>(v);
    v += __shfl_xor(v, 16);
    return v;
}

// ---------------------------------------------------------------------------
// Kernel 1, grid 160:
//   blocks [0,128)  : MFMA split-bf16 GEMM, 64x64 tile, BK=64.
//     g = Hh@Wh + Hh@Wl + Hl@Wh  (split-bf16, f32 accumulate, err ~1e-4)
//     A staged [m][k] bf16 (stride 72), B staged transposed [n][k] bf16.
//     Both fragments read with ds_read_b128, k = (lane>>4)*8 + r for BOTH
//     operands (positional pairing -> any common bijection is exact).
//   blocks [128,160): adjacency bitmask -> CSR neighbor lists (unchanged R8)
// ---------------------------------------------------------------------------
__global__ __launch_bounds__(256) void k_prep(const float* __restrict__ h,
                                              const float* __restrict__ Wl,
                                              const float* __restrict__ Wr,
                                              const int* __restrict__ ei, int E,
                                              float* __restrict__ gl,
                                              float* __restrict__ gr,
                                              int* __restrict__ nbrg,
                                              int* __restrict__ cntg) {
    const int blk = blockIdx.x;
    const int t = threadIdx.x;

    if (blk < 128) {
        const int z  = blk & 1;
        const int bn = ((blk >> 1) & 3) * 64;
        const int bm = (blk >> 3) * 64;
        const float* W = z ? Wr : Wl;
        float* outg = z ? gr : gl;

        __shared__ unsigned short Ah[64 * 72];
        __shared__ unsigned short Al[64 * 72];
        __shared__ unsigned short Bh[64 * 72];   // transposed: [n][k]
        __shared__ unsigned short Bl[64 * 72];

        // loader A: row m_ld, 16 consecutive k at kq
        const int m_ld = t >> 2;
        const int kq   = (t & 3) << 4;
        const float* Ap = &h[(bm + m_ld) * EMBED + kq];
        // loader B: rows k=2kp,2kp+1, cols n0..n0+7
        const int kp = t >> 3;
        const int n0 = (t & 7) << 3;
        const float* Bp = &W[(2 * kp) * EMBED + bn + n0];

        const int wid = t >> 6, lane = t & 63;
        const int wr = wid >> 1, wc = wid & 1;
        const int l16 = lane & 15, g = lane >> 4;

        f32x4 acc[2][2];
#pragma unroll
        for (int mi = 0; mi < 2; ++mi)
#pragma unroll
            for (int ni = 0; ni < 2; ++ni) acc[mi][ni] = (f32x4)(0.f);

        for (int kt = 0; kt < 4; ++kt) {
            const int K0 = kt * 64;
            float4 a0 = *(const float4*)(Ap + K0);
            float4 a1 = *(const float4*)(Ap + K0 + 4);
            float4 a2 = *(const float4*)(Ap + K0 + 8);
            float4 a3 = *(const float4*)(Ap + K0 + 12);
            float4 b0 = *(const float4*)(Bp + (size_t)K0 * EMBED);
            float4 b1 = *(const float4*)(Bp + (size_t)K0 * EMBED + 4);
            float4 b2 = *(const float4*)(Bp + (size_t)(K0 + 1) * EMBED);
            float4 b3 = *(const float4*)(Bp + (size_t)(K0 + 1) * EMBED + 4);

            __syncthreads();   // prev compute done before overwrite

            // ---- A: split + store 16 bf16 (hi, lo) ----
            {
                float av[16] = {a0.x, a0.y, a0.z, a0.w, a1.x, a1.y, a1.z, a1.w,
                                a2.x, a2.y, a2.z, a2.w, a3.x, a3.y, a3.z, a3.w};
                unsigned short hi[16], lo[16];
#pragma unroll
                for (int j = 0; j < 16; ++j) {
                    hi[j] = f32_to_bf16(av[j]);
                    lo[j] = f32_to_bf16(av[j] - bf16_to_f32(hi[j]));
                }
                const int base = m_ld * 72 + kq;
#pragma unroll
                for (int q = 0; q < 4; ++q) {
                    *(ushort4*)&Ah[base + q * 4] =
                        make_ushort4(hi[q*4], hi[q*4+1], hi[q*4+2], hi[q*4+3]);
                    *(ushort4*)&Al[base + q * 4] =
                        make_ushort4(lo[q*4], lo[q*4+1], lo[q*4+2], lo[q*4+3]);
                }
            }
            // ---- B: split + store transposed [n][k] ----
            {
                float r0[8] = {b0.x, b0.y, b0.z, b0.w, b1.x, b1.y, b1.z, b1.w};
                float r1[8] = {b2.x, b2.y, b2.z, b2.w, b3.x, b3.y, b3.z, b3.w};
#pragma unroll
                for (int j = 0; j < 8; ++j) {
                    unsigned short h0 = f32_to_bf16(r0[j]);
                    unsigned short h1 = f32_to_bf16(r1[j]);
                    unsigned short l0 = f32_to_bf16(r0[j] - bf16_to_f32(h0));
                    unsigned short l1 = f32_to_bf16(r1[j] - bf16_to_f32(h1));
                    const int base = (n0 + j) * 72 + 2 * kp;
                    *(unsigned int*)&Bh[base] = (unsigned int)h0 | ((unsigned int)h1 << 16);
                    *(unsigned int*)&Bl[base] = (unsigned int)l0 | ((unsigned int)l1 << 16);
                }
            }
            __syncthreads();

            // ---- MFMA compute: 2 k-steps of 32 ----
#pragma unroll
            for (int ks = 0; ks < 2; ++ks) {
                const int kk = ks * 32 + g * 8;
                short8 ah[2], al[2], bh[2], bl[2];
#pragma unroll
                for (int mi = 0; mi < 2; ++mi) {
                    const int r = (wr * 32 + mi * 16 + l16) * 72 + kk;
                    ah[mi] = *(const short8*)&Ah[r];
                    al[mi] = *(const short8*)&Al[r];
                }
#pragma unroll
                for (int ni = 0; ni < 2; ++ni) {
                    const int r = (wc * 32 + ni * 16 + l16) * 72 + kk;
                    bh[ni] = *(const short8*)&Bh[r];
                    bl[ni] = *(const short8*)&Bl[r];
                }
#pragma unroll
                for (int mi = 0; mi < 2; ++mi)
#pragma unroll
                    for (int ni = 0; ni < 2; ++ni) {
                        acc[mi][ni] = __builtin_amdgcn_mfma_f32_16x16x32_bf16(
                            ah[mi], bh[ni], acc[mi][ni], 0, 0, 0);
                        acc[mi][ni] = __builtin_amdgcn_mfma_f32_16x16x32_bf16(
                            ah[mi], bl[ni], acc[mi][ni], 0, 0, 0);
                        acc[mi][ni] = __builtin_amdgcn_mfma_f32_16x16x32_bf16(
                            al[mi], bh[ni], acc[mi][ni], 0, 0, 0);
                    }
            }
        }

        // ---- epilogue: C/D layout col=lane&15, row=(lane>>4)*4+reg ----
#pragma unroll
        for (int mi = 0; mi < 2; ++mi)
#pragma unroll
            for (int ni = 0; ni < 2; ++ni) {
                const int col = bn + wc * 32 + ni * 16 + l16;
#pragma unroll
                for (int p = 0; p < 4; ++p) {
                    const int row = bm + wr * 32 + mi * 16 + g * 4 + p;
                    outg[row * EMBED + col] = acc[mi][ni][p];
                }
            }
    } else {
        // ---- adjacency bitmask + CSR compaction for rows [lo, lo+32) -------
        const int lo = (blk - 128) * 32;
        __shared__ unsigned int lads[1024];
#pragma unroll
        for (int u = 0; u < 4; ++u) lads[t + u * 256] = 0u;
        __syncthreads();

        const int4* ei4 = reinterpret_cast<const int4*>(ei);
        const int nvec = E >> 1;
        int base = 0;
        for (; base + 2048 <= nvec; base += 2048) {
#pragma unroll 8
            for (int u = 0; u < 8; ++u) {
                int4 v = ei4[base + u * 256 + t];
                int r0 = v.x - lo;
                if ((unsigned)r0 < 32u)
                    atomicOr(&lads[r0 * 32 + ((unsigned)v.y >> 5)], 1u << (v.y & 31));
                int r1 = v.z - lo;
                if ((unsigned)r1 < 32u)
                    atomicOr(&lads[r1 * 32 + ((unsigned)v.w >> 5)], 1u << (v.w & 31));
            }
        }
        for (int idx = base + t; idx < nvec; idx += 256) {
            int4 v = ei4[idx];
            int r0 = v.x - lo;
            if ((unsigned)r0 < 32u)
                atomicOr(&lads[r0 * 32 + ((unsigned)v.y >> 5)], 1u << (v.y & 31));
            int r1 = v.z - lo;
            if ((unsigned)r1 < 32u)
                atomicOr(&lads[r1 * 32 + ((unsigned)v.w >> 5)], 1u << (v.w & 31));
        }
        __syncthreads();

        const int wv = t >> 6, ln = t & 63;
        for (int rl = wv * 8; rl < wv * 8 + 8; ++rl) {
            unsigned int w = (ln < 32) ? lads[rl * 32 + ln] : 0u;
            int c = __popc(w);
            int pre = c;
#pragma unroll
            for (int d = 1; d < 32; d <<= 1) {
                int v = __shfl_up(pre, d);
                if (ln >= d) pre += v;
            }
            int tot = __shfl(pre, 31);
            int off = pre - c;
            if (ln == 0) cntg[lo + rl] = tot;
            while (w) {
                int b = __builtin_ctz(w);
                w &= w - 1;
                if (off < DEGMAX) nbrg[(lo + rl) * DEGMAX + off] = ln * 32 + b;
                ++off;
            }
        }
    }
}

// ---------------------------------------------------------------------------
// Kernel 2: per-destination-row softmax + aggregate, CSR-direct (R8).
// ---------------------------------------------------------------------------
__global__ __launch_bounds__(256) void k_attn(const float* __restrict__ gl,
                                              const float* __restrict__ gr,
                                              const int* __restrict__ nbrg,
                                              const int* __restrict__ cntg,
                                              const float* __restrict__ attn_w,
                                              float* __restrict__ out) {
    const int i = blockIdx.x;
    const int t = threadIdx.x;

    __shared__ int nbr_s[DEGMAX];
    __shared__ int cnt_sh;

    if (t == 0) cnt_sh = cntg[i];
    if (t < DEGMAX) nbr_s[t] = nbrg[i * DEGMAX + t];
    __syncthreads();

    const int cnt = cnt_sh;
    const float grv = gr[i * EMBED + t];
    const float aw = attn_w[t & 31];

    float m = -3e38f, s = 0.f, acc = 0.f;

    float g[4];
#pragma unroll
    for (int u = 0; u < 4; ++u) {
        int e = (u < cnt) ? u : cnt - 1;
        g[u] = gl[nbr_s[e] * EMBED + t];
    }

    for (int e0 = 0; e0 < cnt; e0 += 4) {
        float cg[4];
#pragma unroll
        for (int u = 0; u < 4; ++u) cg[u] = g[u];
#pragma unroll
        for (int u = 0; u < 4; ++u) {
            int e = e0 + 4 + u;
            e = (e < cnt) ? e : cnt - 1;
            g[u] = gl[nbr_s[e] * EMBED + t];
        }
        float p[4];
#pragma unroll
        for (int u = 0; u < 4; ++u) {
            float x = cg[u] + grv;
            p[u] = group32_sum((x > 0.f ? x : SLOPE * x) * aw);
        }
        float pm = p[0];
#pragma unroll
        for (int u = 1; u < 4; ++u)
            if (e0 + u < cnt) pm = fmaxf(pm, p[u]);
        float mn = fmaxf(m, pm);
        float sc = __expf(m - mn);
        float ev[4];
#pragma unroll
        for (int u = 0; u < 4; ++u)
            ev[u] = (e0 + u < cnt) ? __expf(p[u] - mn) : 0.f;
        s = s * sc + ((ev[0] + ev[1]) + (ev[2] + ev[3]));
        acc = acc * sc + ((ev[0] * cg[0] + ev[1] * cg[1]) + (ev[2] * cg[2] + ev[3] * cg[3]));
        m = mn;
    }
    out[i * EMBED + t] = acc / s;
}

extern "C" void kernel_launch(void* const* d_in, const int* in_sizes, int n_in,
                              void* d_out, int out_size, void* d_ws, size_t ws_size,
                              hipStream_t stream) {
    const float* h  = (const float*)d_in[0];
    const int*   ei = (const int*)d_in[1];
    const float* Wl = (const float*)d_in[2];
    const float* Wr = (const float*)d_in[3];
    const float* aw = (const float*)d_in[4];
    float* out = (float*)d_out;
    const int E = in_sizes[1] / 2;

    int* nbrg = (int*)d_ws;                                      // 256 KB
    int* cntg = (int*)((char*)d_ws + NN * DEGMAX * 4);           // 4 KB
    float* gl = (float*)((char*)d_ws + NN * DEGMAX * 4 + 4096);  // 1 MB
    float* gr = gl + NN * EMBED;                                 // 1 MB

    k_prep<<<160, 256, 0, stream>>>(h, Wl, Wr, ei, E, gl, gr, nbrg, cntg);
    k_attn<<<NN, 256, 0, stream>>>(gl, gr, nbrg, cntg, aw, out);
}